// Round 20
// baseline (81.848 us; speedup 1.0000x reference)
//
#include <hip/hip_runtime.h>
#include <hip/hip_bf16.h>
#include <cstdint>

#define BATCH  2
#define SEQ    2048
#define DMODEL 1024
#define NH     16
#define DH     64

typedef short bf16x8 __attribute__((ext_vector_type(8)));
typedef float f32x4  __attribute__((ext_vector_type(4)));
typedef unsigned short u16;

#define MFMA16(a, b, c) __builtin_amdgcn_mfma_f32_16x16x32_bf16((a), (b), (c), 0, 0, 0)

#define GLL(gp, lp) __builtin_amdgcn_global_load_lds( \
    (const __attribute__((address_space(1))) void*)(gp), \
    (__attribute__((address_space(3))) void*)(lp), 16, 0, 0)

// score scale 1/sqrt(64) folded with log2(e); baked into Wq at transpose time
#define SCL 0.18033688011112042f

#if __has_builtin(__builtin_amdgcn_exp2f)
#define EXP2(x) __builtin_amdgcn_exp2f(x)
#else
#define EXP2(x) __expf((x) * 0.69314718055994531f)
#endif

static __device__ __forceinline__ u16 f2bf(float f) {
  union { float f; unsigned int i; } u; u.f = f;
  unsigned int r = u.i + 0x7FFFu + ((u.i >> 16) & 1u);  // round-nearest-even
  return (u16)(r >> 16);
}

// ---------------- merged prep: x fp32->bf16 (blocks 0..2047) +
// W [k][n] fp32 -> Wt [n][k] bf16, Wq scaled (blocks 2048..5119) ----------------
__global__ __launch_bounds__(256) void prep_kernel(const float* __restrict__ X,
                                                   const float* __restrict__ W0,
                                                   const float* __restrict__ W1,
                                                   const float* __restrict__ W2,
                                                   u16* __restrict__ Xb,
                                                   u16* __restrict__ Wt) {
  const int wg = blockIdx.x;
  const int t = threadIdx.x;
  if (wg < 2048) {
    int idx = (wg * 256 + t) * 8;
    float4 a = *reinterpret_cast<const float4*>(X + idx);
    float4 b = *reinterpret_cast<const float4*>(X + idx + 4);
    union { bf16x8 v; u16 u[8]; } pk;
    pk.u[0]=f2bf(a.x); pk.u[1]=f2bf(a.y); pk.u[2]=f2bf(a.z); pk.u[3]=f2bf(a.w);
    pk.u[4]=f2bf(b.x); pk.u[5]=f2bf(b.y); pk.u[6]=f2bf(b.z); pk.u[7]=f2bf(b.w);
    *reinterpret_cast<bf16x8*>(Xb + idx) = pk.v;
    return;
  }
  __shared__ float T[32][33];
  const int i = wg - 2048;            // 0..3071
  const int z = i >> 10;              // which W
  const int rem = i & 1023;
  const int k0 = (rem & 31) * 32, n0 = (rem >> 5) * 32;
  const float* W = (z == 0) ? W0 : (z == 1) ? W1 : W2;
  const float sc = (z == 0) ? SCL : 1.0f;
  u16* out = Wt + (size_t)z * DMODEL * DMODEL;
  {
    int r = t >> 3, c = (t & 7) * 4;
    float4 v = *reinterpret_cast<const float4*>(W + (size_t)(k0 + r) * DMODEL + n0 + c);
    T[r][c] = v.x; T[r][c+1] = v.y; T[r][c+2] = v.z; T[r][c+3] = v.w;
  }
  __syncthreads();
  {
    int n = t >> 3, k = (t & 7) * 4;
    union { unsigned long long ll; u16 u[4]; } pk;
    pk.u[0] = f2bf(T[k][n] * sc);   pk.u[1] = f2bf(T[k+1][n] * sc);
    pk.u[2] = f2bf(T[k+2][n] * sc); pk.u[3] = f2bf(T[k+3][n] * sc);
    *reinterpret_cast<unsigned long long*>(out + (size_t)(n0 + n) * DMODEL + k0 + k) = pk.ll;
  }
}

// ---------------- QKV GEMM: Y[b,h,s,dh](bf16) = Xb[bs][k] * Wt[n][k]^T ----------
__global__ __launch_bounds__(256) void qkv_mfma_kernel(const u16* __restrict__ Xb,
                                                       const u16* __restrict__ Wt,
                                                       u16* __restrict__ Y) {
  __shared__ u16 As[128 * 64];
  __shared__ u16 Bs[128 * 64];
  char* Ab = (char*)As; char* Bb = (char*)Bs;
  const int t = threadIdx.x;
  const int lane = t & 63;
  const int w = t >> 6;
  const int wr = w >> 1, wc = w & 1;
  const int l15 = lane & 15, lg = lane >> 4;
  const int row0 = blockIdx.x * 128;
  const int col0 = blockIdx.y * 128;
  const int z = blockIdx.z;
  const u16* Wz = Wt + (size_t)z * DMODEL * DMODEL;
  u16* Yz = Y + (size_t)z * ((size_t)BATCH * SEQ * DMODEL);

  f32x4 acc[4][4];
  #pragma unroll
  for (int mt = 0; mt < 4; ++mt)
    #pragma unroll
    for (int nt = 0; nt < 4; ++nt)
      acc[mt][nt] = (f32x4){0.f, 0.f, 0.f, 0.f};

  size_t aofs[4], bofs[4];
  #pragma unroll
  for (int it = 0; it < 4; ++it) {
    int row = it * 32 + (t >> 3);
    int sl  = (t & 7) ^ (row & 7);
    aofs[it] = (size_t)(row0 + row) * DMODEL + sl * 8;
    bofs[it] = (size_t)(col0 + row) * DMODEL + sl * 8;
  }

  for (int k0 = 0; k0 < DMODEL; k0 += 64) {
    __syncthreads();
    #pragma unroll
    for (int it = 0; it < 4; ++it) {
      GLL(Xb + aofs[it] + k0, Ab + it * 4096 + w * 1024);
      GLL(Wz + bofs[it] + k0, Bb + it * 4096 + w * 1024);
    }
    __syncthreads();   // implicit vmcnt(0): staged data landed
    #pragma unroll
    for (int c = 0; c < 2; ++c) {
      bf16x8 am[4], bn[4];
      int kof = c * 64 + lg * 16;
      #pragma unroll
      for (int mt = 0; mt < 4; ++mt) {
        int row = wr * 64 + mt * 16 + l15;
        am[mt] = *reinterpret_cast<const bf16x8*>(Ab + row * 128 + (kof ^ ((row & 7) << 4)));
      }
      #pragma unroll
      for (int nt = 0; nt < 4; ++nt) {
        int row = wc * 64 + nt * 16 + l15;
        bn[nt] = *reinterpret_cast<const bf16x8*>(Bb + row * 128 + (kof ^ ((row & 7) << 4)));
      }
      #pragma unroll
      for (int mt = 0; mt < 4; ++mt)
        #pragma unroll
        for (int nt = 0; nt < 4; ++nt)
          acc[mt][nt] = MFMA16(am[mt], bn[nt], acc[mt][nt]);
    }
  }

  #pragma unroll
  for (int mt = 0; mt < 4; ++mt) {
    #pragma unroll
    for (int i = 0; i < 4; ++i) {
      int bs = row0 + wr * 64 + mt * 16 + lg * 4 + i;
      int b = bs >> 11, s = bs & (SEQ - 1);
      #pragma unroll
      for (int nt = 0; nt < 4; ++nt) {
        int d = col0 + wc * 64 + nt * 16 + l15;
        int h = d >> 6, dd = d & (DH - 1);
        size_t off = (((size_t)b * NH + h) * SEQ + s) * DH + dd;
        Yz[off] = f2bf(acc[mt][nt][i]);
      }
    }
  }
}

// ---------------- V [b,h,s,dh] -> Vt [b,h,dh,s] ----------------
__global__ __launch_bounds__(256) void transpose_v_kernel(const u16* __restrict__ V,
                                                          u16* __restrict__ Vt) {
  __shared__ u16 L[64][72];
  const int sb = blockIdx.x, h = blockIdx.y, b = blockIdx.z;
  const size_t hin  = ((size_t)b * NH + h) * (size_t)SEQ * DH;
  const size_t hout = ((size_t)b * NH + h) * (size_t)DH * SEQ;
  const int s0 = sb * 64;
  const int t = threadIdx.x;
  const int r = t >> 3, c = t & 7;
  #pragma unroll
  for (int it = 0; it < 2; ++it) {
    int row = r + it * 32;
    bf16x8 v = *reinterpret_cast<const bf16x8*>(V + hin + (size_t)(s0 + row) * DH + c * 8);
    *reinterpret_cast<bf16x8*>(&L[row][c * 8]) = v;
  }
  __syncthreads();
  #pragma unroll
  for (int it = 0; it < 2; ++it) {
    int d = r + it * 32;
    union { bf16x8 v; u16 u[8]; } pk;
    #pragma unroll
    for (int j = 0; j < 8; ++j) pk.u[j] = L[c * 8 + j][d];
    *reinterpret_cast<bf16x8*>(Vt + hout + (size_t)d * SEQ + s0 + c * 8) = pk.v;
  }
}

// stage 64-key K and V tile (kb) into the single 8KB buffers (4 GLL per thread)
#define STAGE_KV(kb)                                                  \
  {                                                                   \
    const u16* kp_ = Kw + hq + (size_t)(kb) * (64 * DH);              \
    const u16* vp_ = Vt + hv + (size_t)(kb) * 64;                     \
    char* kd_ = (char*)Ks + dstb;                                     \
    char* vd_ = (char*)Vs + dstb;                                     \
    GLL(kp_ + kofs0, kd_);        GLL(vp_ + vofs0, vd_);              \
    GLL(kp_ + kofs1, kd_ + 1024); GLL(vp_ + vofs1, vd_ + 1024);       \
  }

// ---------------- Flash attention: KVBLK=64, 24KB LDS (-> ~6 blocks/CU),
// balanced qt mapping (per-CU nkv sums uniform), no-max exp2 softmax,
// swapped QK^T, single affine base for K/V/P reads (dual-base ^64) ----
__global__ __launch_bounds__(256) void flash_mfma14_kernel(const u16* __restrict__ Qw,
                                                           const u16* __restrict__ Kw,
                                                           const u16* __restrict__ Vt,
                                                           float* __restrict__ Out) {
  __shared__ u16 Ks[64 * 64];         // key(64) x d(64), chunk-swizzled (8KB)
  __shared__ u16 Vs[64 * 64];         // d(64) x key(64), chunk-swizzled (8KB)
  __shared__ u16 Pl[4][16 * 64];      // per-wave P [q(16) x key(64)], swizzled (8KB)
  const int wgid = blockIdx.x;
  const int g = wgid & 31;            // head-group; XCD pinned: g%8 == wgid%8
  const int j = (wgid >> 5) & 7;
  const int r = wgid >> 8;            // 0..3
  const int qt = r * 8 + ((r & 1) ? (7 - j) : j);   // balanced: CU-mate nkv sums uniform
  const int b = g >> 4, h = g & 15;
  const int nkv = qt + 1;             // 64-key tiles

  const int t = threadIdx.x, lane = t & 63, w = t >> 6;
  const int l15 = lane & 15, lg = lane >> 4;
  char* Pb = (char*)Pl[w];
  const size_t hq = ((size_t)b * NH + h) * (size_t)SEQ * DH;
  const size_t hv = ((size_t)b * NH + h) * (size_t)DH * SEQ;

  // staging: per-lane pre-swizzled source offsets; linear LDS dest (wave 2KB quarter)
  int kofs0, kofs1, vofs0, vofs1;
  {
    int i0 = (w * 2 + 0) * 64 + lane, i1 = (w * 2 + 1) * 64 + lane;
    int r0 = i0 >> 3, s0 = i0 & 7;
    int r1 = i1 >> 3, s1 = i1 & 7;
    kofs0 = r0 * DH  + ((s0 ^ (r0 & 7)) * 8);
    kofs1 = r1 * DH  + ((s1 ^ (r1 & 7)) * 8);
    vofs0 = r0 * SEQ + ((s0 ^ (r0 & 7)) * 8);
    vofs1 = r1 * SEQ + ((s1 ^ (r1 & 7)) * 8);
  }
  const int dstb = w * 2048;

  // shared affine read base for K/V/P (128B rows): rb0 covers low-64B half, ^64 high
  const int csel = (l15 & 4) << 4;
  const int sw45 = (lg * 16) ^ ((l15 & 3) << 4);
  const int rb0  = l15 * 128 + sw45 + csel;
  const int rb1  = rb0 ^ 64;
  // P-write bases (b64 writes; same per-row XOR ((l15&7)<<4), separable in kt/lg)
  const int pw0  = l15 * 128 + ((lg * 8) ^ ((l15 & 1) << 4));
  const int xw   = ((l15 >> 1) & 3) << 5;

  const int q0 = qt * 64;
  const int qrow = q0 + w * 16 + l15;

  // Q fragment: B-operand of swapped QK (Wq pre-scaled -> log2-domain scores)
  bf16x8 qf0, qf1;
  {
    const u16* qp = Qw + hq + (size_t)qrow * DH + lg * 8;
    qf0 = *reinterpret_cast<const bf16x8*>(qp);
    qf1 = *reinterpret_cast<const bf16x8*>(qp + 32);
  }

  f32x4 o[4];
  #pragma unroll
  for (int dt = 0; dt < 4; ++dt) o[dt] = (f32x4){0.f, 0.f, 0.f, 0.f};
  float l_ = 0.f;   // partial row sum for q=qrow (this lane's lg-slice of keys)

  // ---- full (non-diagonal) tiles: branch-free ----
  #pragma unroll 1
  for (int kb = 0; kb < nkv - 1; ++kb) {
    __syncthreads();                  // all waves done consuming previous tile
    STAGE_KV(kb);
    __syncthreads();                  // implicit vmcnt(0): tile landed

    float s[4][4];
    __builtin_amdgcn_s_setprio(1);
    #pragma unroll
    for (int kt = 0; kt < 4; ++kt) {
      f32x4 sa = (f32x4){0.f, 0.f, 0.f, 0.f};
      bf16x8 kf0 = *reinterpret_cast<const bf16x8*>((char*)Ks + rb0 + kt * 2048);
      bf16x8 kf1 = *reinterpret_cast<const bf16x8*>((char*)Ks + rb1 + kt * 2048);
      sa = MFMA16(kf0, qf0, sa);
      sa = MFMA16(kf1, qf1, sa);
      #pragma unroll
      for (int i = 0; i < 4; ++i) s[kt][i] = sa[i];
    }
    __builtin_amdgcn_s_setprio(0);

    // p = exp2(s); accumulate partial l; native-cast pack -> b64 P-writes
    #pragma unroll
    for (int kt = 0; kt < 4; ++kt) {
      union { unsigned long long ll; __hip_bfloat16 bf[4]; } pk;
      #pragma unroll
      for (int i = 0; i < 4; ++i) {
        float e = EXP2(s[kt][i]);
        l_ += e;
        pk.bf[i] = __float2bfloat16(e);
      }
      *reinterpret_cast<unsigned long long*>(Pb + pw0 + ((kt * 32) ^ xw)) = pk.ll;
    }

    // PV: 2 key-chunks via dual base
    __builtin_amdgcn_s_setprio(1);
    {
      bf16x8 pa0 = *reinterpret_cast<const bf16x8*>(Pb + rb0);
      bf16x8 pa1 = *reinterpret_cast<const bf16x8*>(Pb + rb1);
      #pragma unroll
      for (int dt = 0; dt < 4; ++dt) {
        bf16x8 v0 = *reinterpret_cast<const bf16x8*>((char*)Vs + rb0 + dt * 2048);
        bf16x8 v1 = *reinterpret_cast<const bf16x8*>((char*)Vs + rb1 + dt * 2048);
        o[dt] = MFMA16(pa0, v0, o[dt]);
        o[dt] = MFMA16(pa1, v1, o[dt]);
      }
    }
    __builtin_amdgcn_s_setprio(0);
  }

  // ---- diagonal tile (k0 == q0) ----
  {
    const int kb = nkv - 1;
    const int k0 = kb * 64;
    __syncthreads();
    STAGE_KV(kb);
    __syncthreads();

    const int ktlim = w + 1;             // 1..4
    const int kcmax = (w + 2) >> 1;      // 1,1,2,2

    float s[4][4];
    #pragma unroll
    for (int kt = 0; kt < 4; ++kt) {
      if (kt < ktlim) {
        f32x4 sa = (f32x4){0.f, 0.f, 0.f, 0.f};
        bf16x8 kf0 = *reinterpret_cast<const bf16x8*>((char*)Ks + rb0 + kt * 2048);
        bf16x8 kf1 = *reinterpret_cast<const bf16x8*>((char*)Ks + rb1 + kt * 2048);
        sa = MFMA16(kf0, qf0, sa);
        sa = MFMA16(kf1, qf1, sa);
        #pragma unroll
        for (int i = 0; i < 4; ++i) {
          int key = k0 + kt * 16 + lg * 4 + i;
          s[kt][i] = (key > qrow) ? -1e30f : sa[i];
        }
      } else {
        s[kt][0] = -1e30f; s[kt][1] = -1e30f; s[kt][2] = -1e30f; s[kt][3] = -1e30f;
      }
    }

    #pragma unroll
    for (int kt = 0; kt < 4; ++kt) {
      union { unsigned long long ll; __hip_bfloat16 bf[4]; } pk;
      #pragma unroll
      for (int i = 0; i < 4; ++i) {
        float e = EXP2(s[kt][i]);
        l_ += e;
        pk.bf[i] = __float2bfloat16(e);
      }
      *reinterpret_cast<unsigned long long*>(Pb + pw0 + ((kt * 32) ^ xw)) = pk.ll;
    }

    bf16x8 pa0 = *reinterpret_cast<const bf16x8*>(Pb + rb0);
    bf16x8 pa1 = *reinterpret_cast<const bf16x8*>(Pb + rb1);
    #pragma unroll
    for (int kc = 0; kc < 2; ++kc) {
      if (kc >= kcmax) break;
      const int off = kc ? (rb1 - rb0) : 0;  // ^64 expressed as additive delta of bases
      #pragma unroll
      for (int dt = 0; dt < 4; ++dt) {
        bf16x8 vv = *reinterpret_cast<const bf16x8*>((char*)Vs + rb0 + off + dt * 2048);
        o[dt] = MFMA16(kc ? pa1 : pa0, vv, o[dt]);
      }
    }
  }

  // epilogue: reduce l across lg groups, redistribute, normalize, store
  l_ += __shfl_xor(l_, 16);
  l_ += __shfl_xor(l_, 32);
  #pragma unroll
  for (int i = 0; i < 4; ++i) {
    float li = __shfl(l_, (lane & 48) + lg * 4 + i);
    float inv = 1.f / li;
    int q = q0 + w * 16 + lg * 4 + i;
    float* op = Out + ((size_t)b * SEQ + q) * DMODEL + h * DH + l15;
    #pragma unroll
    for (int dt = 0; dt < 4; ++dt) op[dt * 16] = o[dt][i] * inv;
  }
}

extern "C" void kernel_launch(void* const* d_in, const int* in_sizes, int n_in,
                              void* d_out, int out_size, void* d_ws, size_t ws_size,
                              hipStream_t stream) {
  const float* x  = (const float*)d_in[0];
  const float* Wq = (const float*)d_in[1];
  const float* Wk = (const float*)d_in[2];
  const float* Wv = (const float*)d_in[3];
  float* out = (float*)d_out;

  u16* ws  = (u16*)d_ws;
  u16* qkv = ws;                         // 3 x 4,194,304 bf16  (24 MB)
  u16* xb  = ws + 12582912;              // 4,194,304 bf16      ( 8 MB)
  u16* wt  = ws + 16777216;              // 3 x 1,048,576 bf16  ( 6 MB)
  u16* vt  = ws + 19922944;              // 4,194,304 bf16      ( 8 MB)

  prep_kernel<<<5120, 256, 0, stream>>>(x, Wq, Wk, Wv, xb, wt);
  qkv_mfma_kernel<<<dim3(32, 8, 3), 256, 0, stream>>>(xb, wt, qkv);
  transpose_v_kernel<<<dim3(32, NH, BATCH), 256, 0, stream>>>(qkv + 8388608, vt);
  flash_mfma14_kernel<<<1024, 256, 0, stream>>>(qkv, qkv + 4194304, vt, out);
}

// Round 21
// 79.331 us; speedup vs baseline: 1.0317x; 1.0317x over previous
//
#include <hip/hip_runtime.h>
#include <hip/hip_bf16.h>
#include <cstdint>

#define BATCH  2
#define SEQ    2048
#define DMODEL 1024
#define NH     16
#define DH     64

typedef short bf16x8 __attribute__((ext_vector_type(8)));
typedef float f32x4  __attribute__((ext_vector_type(4)));
typedef unsigned short u16;

#define MFMA16(a, b, c) __builtin_amdgcn_mfma_f32_16x16x32_bf16((a), (b), (c), 0, 0, 0)

#define GLL(gp, lp) __builtin_amdgcn_global_load_lds( \
    (const __attribute__((address_space(1))) void*)(gp), \
    (__attribute__((address_space(3))) void*)(lp), 16, 0, 0)

// score scale 1/sqrt(64) folded with log2(e); baked into Wq at transpose time
#define SCL 0.18033688011112042f

#if __has_builtin(__builtin_amdgcn_exp2f)
#define EXP2(x) __builtin_amdgcn_exp2f(x)
#else
#define EXP2(x) __expf((x) * 0.69314718055994531f)
#endif

static __device__ __forceinline__ u16 f2bf(float f) {
  union { float f; unsigned int i; } u; u.f = f;
  unsigned int r = u.i + 0x7FFFu + ((u.i >> 16) & 1u);  // round-nearest-even
  return (u16)(r >> 16);
}

// ---------------- merged prep: x fp32->bf16 (blocks 0..2047) +
// W [k][n] fp32 -> Wt [n][k] bf16, Wq scaled (blocks 2048..5119) ----------------
__global__ __launch_bounds__(256) void prep_kernel(const float* __restrict__ X,
                                                   const float* __restrict__ W0,
                                                   const float* __restrict__ W1,
                                                   const float* __restrict__ W2,
                                                   u16* __restrict__ Xb,
                                                   u16* __restrict__ Wt) {
  const int wg = blockIdx.x;
  const int t = threadIdx.x;
  if (wg < 2048) {
    int idx = (wg * 256 + t) * 8;
    float4 a = *reinterpret_cast<const float4*>(X + idx);
    float4 b = *reinterpret_cast<const float4*>(X + idx + 4);
    union { bf16x8 v; u16 u[8]; } pk;
    pk.u[0]=f2bf(a.x); pk.u[1]=f2bf(a.y); pk.u[2]=f2bf(a.z); pk.u[3]=f2bf(a.w);
    pk.u[4]=f2bf(b.x); pk.u[5]=f2bf(b.y); pk.u[6]=f2bf(b.z); pk.u[7]=f2bf(b.w);
    *reinterpret_cast<bf16x8*>(Xb + idx) = pk.v;
    return;
  }
  __shared__ float T[32][33];
  const int i = wg - 2048;            // 0..3071
  const int z = i >> 10;              // which W
  const int rem = i & 1023;
  const int k0 = (rem & 31) * 32, n0 = (rem >> 5) * 32;
  const float* W = (z == 0) ? W0 : (z == 1) ? W1 : W2;
  const float sc = (z == 0) ? SCL : 1.0f;
  u16* out = Wt + (size_t)z * DMODEL * DMODEL;
  {
    int r = t >> 3, c = (t & 7) * 4;
    float4 v = *reinterpret_cast<const float4*>(W + (size_t)(k0 + r) * DMODEL + n0 + c);
    T[r][c] = v.x; T[r][c+1] = v.y; T[r][c+2] = v.z; T[r][c+3] = v.w;
  }
  __syncthreads();
  {
    int n = t >> 3, k = (t & 7) * 4;
    union { unsigned long long ll; u16 u[4]; } pk;
    pk.u[0] = f2bf(T[k][n] * sc);   pk.u[1] = f2bf(T[k+1][n] * sc);
    pk.u[2] = f2bf(T[k+2][n] * sc); pk.u[3] = f2bf(T[k+3][n] * sc);
    *reinterpret_cast<unsigned long long*>(out + (size_t)(n0 + n) * DMODEL + k0 + k) = pk.ll;
  }
}

// ---------------- QKV GEMM: Y[b,h,s,dh](bf16) = Xb[bs][k] * Wt[n][k]^T ----------
__global__ __launch_bounds__(256) void qkv_mfma_kernel(const u16* __restrict__ Xb,
                                                       const u16* __restrict__ Wt,
                                                       u16* __restrict__ Y) {
  __shared__ u16 As[128 * 64];
  __shared__ u16 Bs[128 * 64];
  char* Ab = (char*)As; char* Bb = (char*)Bs;
  const int t = threadIdx.x;
  const int lane = t & 63;
  const int w = t >> 6;
  const int wr = w >> 1, wc = w & 1;
  const int l15 = lane & 15, lg = lane >> 4;
  const int row0 = blockIdx.x * 128;
  const int col0 = blockIdx.y * 128;
  const int z = blockIdx.z;
  const u16* Wz = Wt + (size_t)z * DMODEL * DMODEL;
  u16* Yz = Y + (size_t)z * ((size_t)BATCH * SEQ * DMODEL);

  f32x4 acc[4][4];
  #pragma unroll
  for (int mt = 0; mt < 4; ++mt)
    #pragma unroll
    for (int nt = 0; nt < 4; ++nt)
      acc[mt][nt] = (f32x4){0.f, 0.f, 0.f, 0.f};

  size_t aofs[4], bofs[4];
  #pragma unroll
  for (int it = 0; it < 4; ++it) {
    int row = it * 32 + (t >> 3);
    int sl  = (t & 7) ^ (row & 7);
    aofs[it] = (size_t)(row0 + row) * DMODEL + sl * 8;
    bofs[it] = (size_t)(col0 + row) * DMODEL + sl * 8;
  }

  for (int k0 = 0; k0 < DMODEL; k0 += 64) {
    __syncthreads();
    #pragma unroll
    for (int it = 0; it < 4; ++it) {
      GLL(Xb + aofs[it] + k0, Ab + it * 4096 + w * 1024);
      GLL(Wz + bofs[it] + k0, Bb + it * 4096 + w * 1024);
    }
    __syncthreads();   // implicit vmcnt(0): staged data landed
    #pragma unroll
    for (int c = 0; c < 2; ++c) {
      bf16x8 am[4], bn[4];
      int kof = c * 64 + lg * 16;
      #pragma unroll
      for (int mt = 0; mt < 4; ++mt) {
        int row = wr * 64 + mt * 16 + l15;
        am[mt] = *reinterpret_cast<const bf16x8*>(Ab + row * 128 + (kof ^ ((row & 7) << 4)));
      }
      #pragma unroll
      for (int nt = 0; nt < 4; ++nt) {
        int row = wc * 64 + nt * 16 + l15;
        bn[nt] = *reinterpret_cast<const bf16x8*>(Bb + row * 128 + (kof ^ ((row & 7) << 4)));
      }
      #pragma unroll
      for (int mt = 0; mt < 4; ++mt)
        #pragma unroll
        for (int nt = 0; nt < 4; ++nt)
          acc[mt][nt] = MFMA16(am[mt], bn[nt], acc[mt][nt]);
    }
  }

  #pragma unroll
  for (int mt = 0; mt < 4; ++mt) {
    #pragma unroll
    for (int i = 0; i < 4; ++i) {
      int bs = row0 + wr * 64 + mt * 16 + lg * 4 + i;
      int b = bs >> 11, s = bs & (SEQ - 1);
      #pragma unroll
      for (int nt = 0; nt < 4; ++nt) {
        int d = col0 + wc * 64 + nt * 16 + l15;
        int h = d >> 6, dd = d & (DH - 1);
        size_t off = (((size_t)b * NH + h) * SEQ + s) * DH + dd;
        Yz[off] = f2bf(acc[mt][nt][i]);
      }
    }
  }
}

// ---------------- V [b,h,s,dh] -> Vt [b,h,dh,s] ----------------
__global__ __launch_bounds__(256) void transpose_v_kernel(const u16* __restrict__ V,
                                                          u16* __restrict__ Vt) {
  __shared__ u16 L[64][72];
  const int sb = blockIdx.x, h = blockIdx.y, b = blockIdx.z;
  const size_t hin  = ((size_t)b * NH + h) * (size_t)SEQ * DH;
  const size_t hout = ((size_t)b * NH + h) * (size_t)DH * SEQ;
  const int s0 = sb * 64;
  const int t = threadIdx.x;
  const int r = t >> 3, c = t & 7;
  #pragma unroll
  for (int it = 0; it < 2; ++it) {
    int row = r + it * 32;
    bf16x8 v = *reinterpret_cast<const bf16x8*>(V + hin + (size_t)(s0 + row) * DH + c * 8);
    *reinterpret_cast<bf16x8*>(&L[row][c * 8]) = v;
  }
  __syncthreads();
  #pragma unroll
  for (int it = 0; it < 2; ++it) {
    int d = r + it * 32;
    union { bf16x8 v; u16 u[8]; } pk;
    #pragma unroll
    for (int j = 0; j < 8; ++j) pk.u[j] = L[c * 8 + j][d];
    *reinterpret_cast<bf16x8*>(Vt + hout + (size_t)d * SEQ + s0 + c * 8) = pk.v;
  }
}

// issue 8 global_load_lds for tile (kb) into the single K/V buffers: linear LDS
// dest, pre-swizzled global source (XOR involution chunk^=row&7 matches reads)
#define STAGE_KV(kb)                                                  \
  {                                                                   \
    const u16* kp_ = Kw + hq + (size_t)(kb) * (128 * DH);             \
    const u16* vp_ = Vt + hv + (size_t)(kb) * 128;                    \
    char* kd_ = (char*)Ks + dstb;                                     \
    char* vd_ = (char*)Vs + dstb;                                     \
    GLL(kp_ + kofs[0], kd_);        GLL(vp_ + vofs[0], vd_);          \
    GLL(kp_ + kofs[1], kd_ + 1024); GLL(vp_ + vofs[1], vd_ + 1024);   \
    GLL(kp_ + kofs[2], kd_ + 2048); GLL(vp_ + vofs[2], vd_ + 2048);   \
    GLL(kp_ + kofs[3], kd_ + 3072); GLL(vp_ + vofs[3], vd_ + 3072);   \
  }

// ---------------- Flash attention (R18/R19-proven): unpaired q-tiles (1024
// blocks, LPT order), KVBLK=128, single-buffer GLL staging (48KB -> 3 blocks/CU
// + refill queue), no-max exp2 softmax, swapped QK^T, affine LDS-read bases ----
__global__ __launch_bounds__(256) void flash_mfma13_kernel(const u16* __restrict__ Qw,
                                                           const u16* __restrict__ Kw,
                                                           const u16* __restrict__ Vt,
                                                           float* __restrict__ Out) {
  __shared__ u16 Ks[128 * 64];        // key(128) x d(64), chunk-swizzled content (16KB)
  __shared__ u16 Vs[64 * 128];        // d(64) x key(128), chunk-swizzled content (16KB)
  __shared__ u16 Pl[4][16 * 128];     // per-wave P [q(16) x key(128)], swizzled (16KB)
  const int wgid = blockIdx.x;
  const int g = wgid & 31;            // head-group; XCD pinned: g%8 == wgid%8
  const int qt = 31 - (wgid >> 5);    // LPT: longest q-tiles dispatched first
  const int b = g >> 4, h = g & 15;
  const int t = threadIdx.x, lane = t & 63, w = t >> 6;
  const int l15 = lane & 15, lg = lane >> 4;
  char* Pb = (char*)Pl[w];
  const size_t hq = ((size_t)b * NH + h) * (size_t)SEQ * DH;
  const size_t hv = ((size_t)b * NH + h) * (size_t)DH * SEQ;

  // per-lane staging source offsets (elements) + wave-uniform LDS dest base
  size_t kofs[4], vofs[4];
  #pragma unroll
  for (int it = 0; it < 4; ++it) {
    int i = (w * 4 + it) * 64 + lane;
    kofs[it] = (size_t)(i >> 3) * DH + (size_t)((((i & 7) ^ ((i >> 3) & 7))) * 8);
    vofs[it] = (size_t)(i >> 4) * SEQ + (size_t)((((i & 15) ^ ((i >> 4) & 7))) * 8);
  }
  const int dstb = w * 4096;

  // affine LDS read bases: bits4,5 of the XOR fold into the base; bit6 -> dual bases
  const int csel = (l15 & 4) << 4;
  const int sw45 = (lg * 16) ^ ((l15 & 3) << 4);
  const int kb0  = l15 * 128 + sw45 + csel;
  const int kb1  = kb0 ^ 64;
  const int vbA  = l15 * 256 + sw45 + csel;
  const int vbB  = vbA ^ 64;
  const int pw0  = l15 * 256 + ((lg * 8) ^ ((l15 & 1) << 4));
  const int xw   = ((l15 >> 1) & 3) << 5;

  const int q0 = qt * 64;
  const int nkv = (qt >> 1) + 1;
  const int qrow = q0 + w * 16 + l15;

  // Q fragment: B-operand of swapped QK (Wq pre-scaled -> log2-domain scores)
  bf16x8 qf0, qf1;
  {
    const u16* qp = Qw + hq + (size_t)qrow * DH + lg * 8;
    qf0 = *reinterpret_cast<const bf16x8*>(qp);
    qf1 = *reinterpret_cast<const bf16x8*>(qp + 32);
  }

  f32x4 o[4];
  #pragma unroll
  for (int dt = 0; dt < 4; ++dt) o[dt] = (f32x4){0.f, 0.f, 0.f, 0.f};
  float l_ = 0.f;   // partial row sum for q=qrow (this lane's lg-slice of keys)

  // ---- full (non-diagonal) tiles: branch-free ----
  #pragma unroll 1
  for (int kb = 0; kb < nkv - 1; ++kb) {
    __syncthreads();                  // all waves done consuming previous tile
    STAGE_KV(kb);
    __syncthreads();                  // implicit vmcnt(0): tile landed

    float s[8][4];
    __builtin_amdgcn_s_setprio(1);
    #pragma unroll
    for (int kt = 0; kt < 8; ++kt) {
      f32x4 sa = (f32x4){0.f, 0.f, 0.f, 0.f};
      bf16x8 kf0 = *reinterpret_cast<const bf16x8*>((char*)Ks + kb0 + kt * 2048);
      bf16x8 kf1 = *reinterpret_cast<const bf16x8*>((char*)Ks + kb1 + kt * 2048);
      sa = MFMA16(kf0, qf0, sa);
      sa = MFMA16(kf1, qf1, sa);
      #pragma unroll
      for (int i = 0; i < 4; ++i) s[kt][i] = sa[i];
    }
    __builtin_amdgcn_s_setprio(0);

    // p = exp2(s); accumulate partial l; native-cast pack -> b64 P-writes
    #pragma unroll
    for (int kt = 0; kt < 8; ++kt) {
      union { unsigned long long ll; __hip_bfloat16 bf[4]; } pk;
      #pragma unroll
      for (int i = 0; i < 4; ++i) {
        float e = EXP2(s[kt][i]);
        l_ += e;
        pk.bf[i] = __float2bfloat16(e);
      }
      *reinterpret_cast<unsigned long long*>(Pb + pw0 + ((kt * 32) ^ xw)) = pk.ll;
    }

    // PV (dual-base form, all 4 key-chunks)
    __builtin_amdgcn_s_setprio(1);
    {
      bf16x8 pa0 = *reinterpret_cast<const bf16x8*>(Pb + vbA);
      bf16x8 pa1 = *reinterpret_cast<const bf16x8*>(Pb + vbB);
      bf16x8 pa2 = *reinterpret_cast<const bf16x8*>(Pb + vbA + 128);
      bf16x8 pa3 = *reinterpret_cast<const bf16x8*>(Pb + vbB + 128);
      #pragma unroll
      for (int dt = 0; dt < 4; ++dt) {
        bf16x8 v0 = *reinterpret_cast<const bf16x8*>((char*)Vs + vbA + dt * 4096);
        bf16x8 v1 = *reinterpret_cast<const bf16x8*>((char*)Vs + vbB + dt * 4096);
        bf16x8 v2 = *reinterpret_cast<const bf16x8*>((char*)Vs + vbA + 128 + dt * 4096);
        bf16x8 v3 = *reinterpret_cast<const bf16x8*>((char*)Vs + vbB + 128 + dt * 4096);
        o[dt] = MFMA16(pa0, v0, o[dt]);
        o[dt] = MFMA16(pa1, v1, o[dt]);
        o[dt] = MFMA16(pa2, v2, o[dt]);
        o[dt] = MFMA16(pa3, v3, o[dt]);
      }
    }
    __builtin_amdgcn_s_setprio(0);
  }

  // ---- diagonal tile ----
  {
    const int kb = nkv - 1;
    const int k0 = kb * 128;
    __syncthreads();
    STAGE_KV(kb);
    __syncthreads();

    const int qmax = q0 + w * 16 + 15;
    const int ktlim = ((qmax - k0) >> 4) + 1;    // 1..8
    const int kcmax = (ktlim + 1) >> 1;

    float s[8][4];
    #pragma unroll
    for (int kt = 0; kt < 8; ++kt) {
      if (kt < ktlim) {
        f32x4 sa = (f32x4){0.f, 0.f, 0.f, 0.f};
        bf16x8 kf0 = *reinterpret_cast<const bf16x8*>((char*)Ks + kb0 + kt * 2048);
        bf16x8 kf1 = *reinterpret_cast<const bf16x8*>((char*)Ks + kb1 + kt * 2048);
        sa = MFMA16(kf0, qf0, sa);
        sa = MFMA16(kf1, qf1, sa);
        #pragma unroll
        for (int i = 0; i < 4; ++i) {
          int key = k0 + kt * 16 + lg * 4 + i;
          s[kt][i] = (key > qrow) ? -1e30f : sa[i];
        }
      } else {
        s[kt][0] = -1e30f; s[kt][1] = -1e30f; s[kt][2] = -1e30f; s[kt][3] = -1e30f;
      }
    }

    #pragma unroll
    for (int kt = 0; kt < 8; ++kt) {
      union { unsigned long long ll; __hip_bfloat16 bf[4]; } pk;
      #pragma unroll
      for (int i = 0; i < 4; ++i) {
        float e = EXP2(s[kt][i]);
        l_ += e;
        pk.bf[i] = __float2bfloat16(e);
      }
      *reinterpret_cast<unsigned long long*>(Pb + pw0 + ((kt * 32) ^ xw)) = pk.ll;
    }

    bf16x8 paq[4];
    paq[0] = *reinterpret_cast<const bf16x8*>(Pb + vbA);
    paq[1] = *reinterpret_cast<const bf16x8*>(Pb + vbB);
    paq[2] = *reinterpret_cast<const bf16x8*>(Pb + vbA + 128);
    paq[3] = *reinterpret_cast<const bf16x8*>(Pb + vbB + 128);
    #pragma unroll
    for (int kc = 0; kc < 4; ++kc) {
      if (kc >= kcmax) break;
      const int vo = (kc & 1) ? (vbB - vbA) : 0;
      const int hi = (kc >> 1) * 128;
      #pragma unroll
      for (int dt = 0; dt < 4; ++dt) {
        bf16x8 vbf = *reinterpret_cast<const bf16x8*>((char*)Vs + vbA + vo + hi + dt * 4096);
        o[dt] = MFMA16(paq[kc], vbf, o[dt]);
      }
    }
  }

  // epilogue: reduce l across lg groups, redistribute, normalize, store
  l_ += __shfl_xor(l_, 16);
  l_ += __shfl_xor(l_, 32);
  #pragma unroll
  for (int i = 0; i < 4; ++i) {
    float li = __shfl(l_, (lane & 48) + lg * 4 + i);
    float inv = 1.f / li;
    int q = q0 + w * 16 + lg * 4 + i;
    float* op = Out + ((size_t)b * SEQ + q) * DMODEL + h * DH + l15;
    #pragma unroll
    for (int dt = 0; dt < 4; ++dt) op[dt * 16] = o[dt][i] * inv;
  }
}

extern "C" void kernel_launch(void* const* d_in, const int* in_sizes, int n_in,
                              void* d_out, int out_size, void* d_ws, size_t ws_size,
                              hipStream_t stream) {
  const float* x  = (const float*)d_in[0];
  const float* Wq = (const float*)d_in[1];
  const float* Wk = (const float*)d_in[2];
  const float* Wv = (const float*)d_in[3];
  float* out = (float*)d_out;

  u16* ws  = (u16*)d_ws;
  u16* qkv = ws;                         // 3 x 4,194,304 bf16  (24 MB)
  u16* xb  = ws + 12582912;              // 4,194,304 bf16      ( 8 MB)
  u16* wt  = ws + 16777216;              // 3 x 1,048,576 bf16  ( 6 MB)
  u16* vt  = ws + 19922944;              // 4,194,304 bf16      ( 8 MB)

  prep_kernel<<<5120, 256, 0, stream>>>(x, Wq, Wk, Wv, xb, wt);
  qkv_mfma_kernel<<<dim3(32, 8, 3), 256, 0, stream>>>(xb, wt, qkv);
  transpose_v_kernel<<<dim3(32, NH, BATCH), 256, 0, stream>>>(qkv + 8388608, vt);
  flash_mfma13_kernel<<<1024, 256, 0, stream>>>(qkv, qkv + 4194304, vt, out);
}